// Round 1
// baseline (743.537 us; speedup 1.0000x reference)
//
#include <hip/hip_runtime.h>
#include <hip/hip_bf16.h>

typedef __attribute__((ext_vector_type(8))) short short8;
typedef __attribute__((ext_vector_type(4))) short short4v;
typedef __attribute__((ext_vector_type(4))) float f32x4;
using bf16 = __hip_bfloat16;

static __device__ __forceinline__ short bfb(float f) {
  bf16 h = __float2bfloat16(f);
  short r; __builtin_memcpy(&r, &h, 2); return r;
}

// ---------------- fp32 -> bf16 convert ----------------
__global__ __launch_bounds__(256) void cvt_kernel(const float* __restrict__ s,
                                                  bf16* __restrict__ d, int n) {
  int i = (blockIdx.x * 256 + threadIdx.x) * 8;
  if (i >= n) return;
  float4 v0 = *(const float4*)(s + i);
  float4 v1 = *(const float4*)(s + i + 4);
  short8 o;
  o[0] = bfb(v0.x); o[1] = bfb(v0.y); o[2] = bfb(v0.z); o[3] = bfb(v0.w);
  o[4] = bfb(v1.x); o[5] = bfb(v1.y); o[6] = bfb(v1.z); o[7] = bfb(v1.w);
  *(short8*)(d + i) = o;
}

// ---------------- t projections: out[s][b][n] = t[b] . W_s[n] ----------------
__global__ __launch_bounds__(256) void tproj_kernel(const float* __restrict__ t,
    const float* __restrict__ w0, const float* __restrict__ w1, const float* __restrict__ w2,
    const float* __restrict__ w3, const float* __restrict__ w4, const float* __restrict__ w5,
    float* __restrict__ out) {
  int gid = blockIdx.x * 256 + threadIdx.x;       // 6*4*1024 = 24576
  int s = gid >> 12, rem = gid & 4095;
  int b = rem >> 10, n = rem & 1023;
  const float* w = (s == 0) ? w0 : (s == 1) ? w1 : (s == 2) ? w2 : (s == 3) ? w3 : (s == 4) ? w4 : w5;
  const float4* tv = (const float4*)(t + b * 256);
  const float4* wv = (const float4*)(w + n * 256);
  float acc = 0.f;
  #pragma unroll 8
  for (int j = 0; j < 64; ++j) {
    float4 a = tv[j], c = wv[j];
    acc += a.x * c.x + a.y * c.y + a.z * c.z + a.w * c.w;
  }
  out[gid] = acc;
}

// ---------------- AdaRMSNorm: out = bf16(gamma * x * rsqrt(mean(x^2)+eps) + beta) ----------------
__global__ __launch_bounds__(256) void ada_rms_kernel(const float* __restrict__ x,
    const float* __restrict__ gamma, const float* __restrict__ beta, bf16* __restrict__ out) {
  int row = blockIdx.x;            // 8192 rows
  int b = row >> 11;
  int tid = threadIdx.x;
  const float* xr = x + (size_t)row * 1024;
  float4 v = *(const float4*)(xr + tid * 4);
  float ss = v.x * v.x + v.y * v.y + v.z * v.z + v.w * v.w;
  #pragma unroll
  for (int m = 1; m < 64; m <<= 1) ss += __shfl_xor(ss, m);
  __shared__ float red[4];
  if ((tid & 63) == 0) red[tid >> 6] = ss;
  __syncthreads();
  float tot = red[0] + red[1] + red[2] + red[3];
  float rinv = rsqrtf(tot * (1.0f / 1024.0f) + 1e-6f);
  const float* g  = gamma + b * 1024 + tid * 4;
  const float* be = beta  + b * 1024 + tid * 4;
  short4v o;
  o[0] = bfb(g[0] * v.x * rinv + be[0]);
  o[1] = bfb(g[1] * v.y * rinv + be[1]);
  o[2] = bfb(g[2] * v.z * rinv + be[2]);
  o[3] = bfb(g[3] * v.w * rinv + be[3]);
  *(short4v*)(out + (size_t)row * 1024 + tid * 4) = o;
}

// ---------------- bf16 MFMA GEMM: C[M,N] = A[M,K] . B[N,K]^T, fused epilogues ----------------
enum { EPI_HEADS = 0, EPI_VTRANS = 1, EPI_RESID = 2, EPI_BF16 = 3, EPI_SWIGLU = 4, EPI_FINAL = 5 };

template<int EPI>
__global__ __launch_bounds__(256) void gemm_bt_kernel(
    const bf16* __restrict__ A, const bf16* __restrict__ B,
    int M, int N, int K,
    float* __restrict__ outF, bf16* __restrict__ outB,
    const float* __restrict__ aux1, const float* __restrict__ aux2,
    const float* __restrict__ bias, const bf16* __restrict__ gateb)
{
  __shared__ __align__(16) bf16 As[128][40];   // +8 pad: 2-way bank alias only
  __shared__ __align__(16) bf16 Bs[128][40];
  const int tid = threadIdx.x;
  const int lane = tid & 63, wid = tid >> 6;
  const int wr = wid >> 1, wc = wid & 1;              // 2x2 wave grid, 64x64 per wave
  const int ntn = N >> 7;
  const int trow = (int)(blockIdx.x / ntn) << 7;
  const int tcol = (int)(blockIdx.x % ntn) << 7;
  const int srow = tid >> 2, scol = (tid & 3) << 3;   // staging: 2 rows x 8 cols per thread
  const int fr = lane & 15, fc = (lane >> 4) << 3;    // fragment addressing
  const int rbase = (lane >> 4) << 2;
  f32x4 acc[4][4] = {};
  for (int k0 = 0; k0 < K; k0 += 32) {
    const bf16* Ap = A + (size_t)(trow + srow) * K + k0 + scol;
    const bf16* Bp = B + (size_t)(tcol + srow) * K + k0 + scol;
    short8 a0 = *(const short8*)Ap;
    short8 a1 = *(const short8*)(Ap + (size_t)64 * K);
    short8 b0 = *(const short8*)Bp;
    short8 b1 = *(const short8*)(Bp + (size_t)64 * K);
    __syncthreads();
    *(short8*)&As[srow][scol] = a0;
    *(short8*)&As[srow + 64][scol] = a1;
    *(short8*)&Bs[srow][scol] = b0;
    *(short8*)&Bs[srow + 64][scol] = b1;
    __syncthreads();
    short8 af[4], bfr[4];
    #pragma unroll
    for (int m = 0; m < 4; ++m) af[m] = *(const short8*)&As[wr * 64 + m * 16 + fr][fc];
    #pragma unroll
    for (int n = 0; n < 4; ++n) bfr[n] = *(const short8*)&Bs[wc * 64 + n * 16 + fr][fc];
    #pragma unroll
    for (int m = 0; m < 4; ++m)
      #pragma unroll
      for (int n = 0; n < 4; ++n)
        acc[m][n] = __builtin_amdgcn_mfma_f32_16x16x32_bf16(af[m], bfr[n], acc[m][n], 0, 0, 0);
  }
  #pragma unroll
  for (int m = 0; m < 4; ++m)
  #pragma unroll
  for (int n = 0; n < 4; ++n)
  #pragma unroll
  for (int r = 0; r < 4; ++r) {
    int row = trow + wr * 64 + m * 16 + rbase + r;
    int col = tcol + wc * 64 + n * 16 + fr;
    float c = acc[m][n][r];
    if constexpr (EPI == EPI_HEADS) {            // [b,h,l,d] bf16
      int b = row >> 11, l = row & 2047, h = col >> 6, dd = col & 63;
      outB[(((size_t)(b * 16 + h) * 2048 + l) << 6) + dd] = __float2bfloat16(c);
    } else if constexpr (EPI == EPI_VTRANS) {    // [b,h,d,l] bf16
      int b = row >> 11, l = row & 2047, h = col >> 6, dd = col & 63;
      outB[(((size_t)(b * 16 + h) * 64 + dd) << 11) + l] = __float2bfloat16(c);
    } else if constexpr (EPI == EPI_RESID) {     // xmid = x + alpha * c  (fp32)
      int b = row >> 11;
      size_t idx = (size_t)row * 1024 + col;
      outF[idx] = aux1[idx] + aux2[b * 1024 + col] * c;
    } else if constexpr (EPI == EPI_BF16) {      // plain bf16 store
      outB[(size_t)row * N + col] = __float2bfloat16(c);
    } else if constexpr (EPI == EPI_SWIGLU) {    // h = silu(gate) * c, in-place over gate
      size_t idx = (size_t)row * N + col;
      float g = __bfloat162float(gateb[idx]);
      float sg = g / (1.f + __expf(-g));
      outB[idx] = __float2bfloat16(sg * c);
    } else {                                     // EPI_FINAL: out = xmid + alpha*(c + bias)
      int b = row >> 11;
      size_t idx = (size_t)row * 1024 + col;
      outF[idx] = aux1[idx] + aux2[b * 1024 + col] * (c + bias[col]);
    }
  }
}

// ---------------- flash attention (no-max online softmax; scores are tiny) ----------------
__global__ __launch_bounds__(256) void attn_kernel(const bf16* __restrict__ q,
    const bf16* __restrict__ k, const bf16* __restrict__ vt, bf16* __restrict__ o) {
  const int qt = blockIdx.x & 15;
  const int bh = blockIdx.x >> 4;
  const int b = bh >> 4, h = bh & 15;
  __shared__ __align__(16) bf16 Ks[64][72];
  __shared__ __align__(16) bf16 Vs[64][72];   // Vs[d][kk]
  __shared__ __align__(16) bf16 Ps[128][72];
  const int tid = threadIdx.x, lane = tid & 63, w = tid >> 6;
  const int fr = lane & 15, fc = (lane >> 4) << 3;
  const int rbase = (lane >> 4) << 2;
  const bf16* qbase = q + ((size_t)bh * 2048 + qt * 128) * 64;
  const bf16* kbase = k + (size_t)bh * 2048 * 64;
  const bf16* vbase = vt + (size_t)bh * 64 * 2048;
  short8 qf[2][2];
  #pragma unroll
  for (int m = 0; m < 2; ++m)
    #pragma unroll
    for (int ks = 0; ks < 2; ++ks)
      qf[m][ks] = *(const short8*)(qbase + (size_t)(w * 32 + m * 16 + fr) * 64 + ks * 32 + fc);
  f32x4 accO[2][4] = {};
  float den[2][4] = {};
  const float cf = 0.125f * 1.44269504089f;   // scale * log2(e), use exp2
  const int sr = tid >> 3, sc = (tid & 7) << 3;
  for (int kt = 0; kt < 2048; kt += 64) {
    __syncthreads();
    *(short8*)&Ks[sr][sc]      = *(const short8*)(kbase + (size_t)(kt + sr) * 64 + sc);
    *(short8*)&Ks[sr + 32][sc] = *(const short8*)(kbase + (size_t)(kt + sr + 32) * 64 + sc);
    *(short8*)&Vs[sr][sc]      = *(const short8*)(vbase + (size_t)sr * 2048 + kt + sc);
    *(short8*)&Vs[sr + 32][sc] = *(const short8*)(vbase + (size_t)(sr + 32) * 2048 + kt + sc);
    __syncthreads();
    f32x4 sf[2][4] = {};
    #pragma unroll
    for (int ks = 0; ks < 2; ++ks) {
      short8 kf[4];
      #pragma unroll
      for (int n = 0; n < 4; ++n) kf[n] = *(const short8*)&Ks[n * 16 + fr][ks * 32 + fc];
      #pragma unroll
      for (int m = 0; m < 2; ++m)
        #pragma unroll
        for (int n = 0; n < 4; ++n)
          sf[m][n] = __builtin_amdgcn_mfma_f32_16x16x32_bf16(qf[m][ks], kf[n], sf[m][n], 0, 0, 0);
    }
    float pd[2][4] = {};
    #pragma unroll
    for (int m = 0; m < 2; ++m)
      #pragma unroll
      for (int n = 0; n < 4; ++n)
        #pragma unroll
        for (int r = 0; r < 4; ++r) {
          float pv = exp2f(cf * sf[m][n][r]);
          sf[m][n][r] = pv;
          pd[m][r] += pv;
        }
    #pragma unroll
    for (int m = 0; m < 2; ++m)
      #pragma unroll
      for (int r = 0; r < 4; ++r) {
        float v2 = pd[m][r];
        v2 += __shfl_xor(v2, 1); v2 += __shfl_xor(v2, 2);
        v2 += __shfl_xor(v2, 4); v2 += __shfl_xor(v2, 8);
        den[m][r] += v2;
      }
    #pragma unroll
    for (int m = 0; m < 2; ++m)
      #pragma unroll
      for (int n = 0; n < 4; ++n)
        #pragma unroll
        for (int r = 0; r < 4; ++r)
          Ps[w * 32 + m * 16 + rbase + r][n * 16 + fr] = __float2bfloat16(sf[m][n][r]);
    __syncthreads();
    #pragma unroll
    for (int ks2 = 0; ks2 < 2; ++ks2) {
      short8 pa[2];
      #pragma unroll
      for (int m = 0; m < 2; ++m) pa[m] = *(const short8*)&Ps[w * 32 + m * 16 + fr][ks2 * 32 + fc];
      #pragma unroll
      for (int n = 0; n < 4; ++n) {
        short8 vb = *(const short8*)&Vs[n * 16 + fr][ks2 * 32 + fc];
        #pragma unroll
        for (int m = 0; m < 2; ++m)
          accO[m][n] = __builtin_amdgcn_mfma_f32_16x16x32_bf16(pa[m], vb, accO[m][n], 0, 0, 0);
      }
    }
  }
  #pragma unroll
  for (int m = 0; m < 2; ++m)
    #pragma unroll
    for (int n = 0; n < 4; ++n)
      #pragma unroll
      for (int r = 0; r < 4; ++r) {
        float v2 = accO[m][n][r] / den[m][r];
        int qrow = qt * 128 + w * 32 + m * 16 + rbase + r;
        int col = h * 64 + n * 16 + fr;
        o[((size_t)b * 2048 + qrow) * 1024 + col] = __float2bfloat16(v2);
      }
}

extern "C" void kernel_launch(void* const* d_in, const int* in_sizes, int n_in,
                              void* d_out, int out_size, void* d_ws, size_t ws_size,
                              hipStream_t stream) {
  (void)in_sizes; (void)n_in; (void)out_size; (void)ws_size;
  const float* x   = (const float*)d_in[0];
  const float* t   = (const float*)d_in[1];
  const float* agw = (const float*)d_in[2];
  const float* abw = (const float*)d_in[3];
  const float* wq  = (const float*)d_in[4];
  const float* wk  = (const float*)d_in[5];
  const float* wv  = (const float*)d_in[6];
  const float* wo  = (const float*)d_in[7];
  const float* aaw = (const float*)d_in[8];
  const float* fgw = (const float*)d_in[9];
  const float* fbw = (const float*)d_in[10];
  const float* gw  = (const float*)d_in[11];
  const float* hw  = (const float*)d_in[12];
  const float* ow  = (const float*)d_in[13];
  const float* ob  = (const float*)d_in[14];
  const float* faw = (const float*)d_in[15];
  float* out = (float*)d_out;

  char* p = (char*)d_ws;
  auto alloc = [&](size_t bytes) -> char* {
    char* r = p; p += (bytes + 255) & ~(size_t)255; return r;
  };
  float* tp    = (float*)alloc((size_t)6 * 4096 * 4);
  bf16* wq_b   = (bf16*)alloc((size_t)1024 * 1024 * 2);
  bf16* wk_b   = (bf16*)alloc((size_t)1024 * 1024 * 2);
  bf16* wv_b   = (bf16*)alloc((size_t)1024 * 1024 * 2);
  bf16* wo_b   = (bf16*)alloc((size_t)1024 * 1024 * 2);
  bf16* wg_b   = (bf16*)alloc((size_t)4096 * 1024 * 2);
  bf16* wh_b   = (bf16*)alloc((size_t)4096 * 1024 * 2);
  bf16* wout_b = (bf16*)alloc((size_t)1024 * 4096 * 2);
  bf16* xn_b   = (bf16*)alloc((size_t)8192 * 1024 * 2);
  bf16* q_b    = (bf16*)alloc((size_t)8192 * 1024 * 2);
  bf16* k_b    = (bf16*)alloc((size_t)8192 * 1024 * 2);
  bf16* vt_b   = (bf16*)alloc((size_t)8192 * 1024 * 2);
  bf16* ao_b   = (bf16*)alloc((size_t)8192 * 1024 * 2);
  float* xmid  = (float*)alloc((size_t)8192 * 1024 * 4);
  bf16* gh_b   = (bf16*)alloc((size_t)8192 * 4096 * 2);

  // weight converts
  cvt_kernel<<<512,  256, 0, stream>>>(wq, wq_b,   1024 * 1024);
  cvt_kernel<<<512,  256, 0, stream>>>(wk, wk_b,   1024 * 1024);
  cvt_kernel<<<512,  256, 0, stream>>>(wv, wv_b,   1024 * 1024);
  cvt_kernel<<<512,  256, 0, stream>>>(wo, wo_b,   1024 * 1024);
  cvt_kernel<<<2048, 256, 0, stream>>>(gw, wg_b,   4096 * 1024);
  cvt_kernel<<<2048, 256, 0, stream>>>(hw, wh_b,   4096 * 1024);
  cvt_kernel<<<2048, 256, 0, stream>>>(ow, wout_b, 1024 * 4096);
  // t projections: [0]=a_gamma [1]=a_beta [2]=a_alpha [3]=f_gamma [4]=f_beta [5]=f_alpha
  tproj_kernel<<<96, 256, 0, stream>>>(t, agw, abw, aaw, fgw, fbw, faw, tp);
  // attn AdaRMSNorm
  ada_rms_kernel<<<8192, 256, 0, stream>>>(x, tp + 0 * 4096, tp + 1 * 4096, xn_b);
  // QKV
  gemm_bt_kernel<EPI_HEADS> <<<512, 256, 0, stream>>>(xn_b, wq_b, 8192, 1024, 1024, nullptr, q_b,  nullptr, nullptr, nullptr, nullptr);
  gemm_bt_kernel<EPI_HEADS> <<<512, 256, 0, stream>>>(xn_b, wk_b, 8192, 1024, 1024, nullptr, k_b,  nullptr, nullptr, nullptr, nullptr);
  gemm_bt_kernel<EPI_VTRANS><<<512, 256, 0, stream>>>(xn_b, wv_b, 8192, 1024, 1024, nullptr, vt_b, nullptr, nullptr, nullptr, nullptr);
  // attention
  attn_kernel<<<1024, 256, 0, stream>>>(q_b, k_b, vt_b, ao_b);
  // O projection + residual
  gemm_bt_kernel<EPI_RESID><<<512, 256, 0, stream>>>(ao_b, wo_b, 8192, 1024, 1024, xmid, nullptr, x, tp + 2 * 4096, nullptr, nullptr);
  // ffn AdaRMSNorm
  ada_rms_kernel<<<8192, 256, 0, stream>>>(xmid, tp + 3 * 4096, tp + 4 * 4096, xn_b);
  // SwiGLU
  gemm_bt_kernel<EPI_BF16>  <<<2048, 256, 0, stream>>>(xn_b, wg_b, 8192, 4096, 1024, nullptr, gh_b, nullptr, nullptr, nullptr, nullptr);
  gemm_bt_kernel<EPI_SWIGLU><<<2048, 256, 0, stream>>>(xn_b, wh_b, 8192, 4096, 1024, nullptr, gh_b, nullptr, nullptr, nullptr, gh_b);
  // out projection + bias + residual
  gemm_bt_kernel<EPI_FINAL> <<<512, 256, 0, stream>>>(gh_b, wout_b, 8192, 1024, 4096, out, nullptr, xmid, tp + 5 * 4096, ob, nullptr);
}

// Round 2
// 601.937 us; speedup vs baseline: 1.2352x; 1.2352x over previous
//
#include <hip/hip_runtime.h>
#include <hip/hip_bf16.h>

typedef __attribute__((ext_vector_type(8))) short short8;
typedef __attribute__((ext_vector_type(4))) short short4v;
typedef __attribute__((ext_vector_type(4))) float f32x4;
using bf16 = __hip_bfloat16;

static __device__ __forceinline__ short bfb(float f) {
  bf16 h = __float2bfloat16(f);
  short r; __builtin_memcpy(&r, &h, 2); return r;
}

static __device__ __forceinline__ void gld_lds16(const bf16* g, bf16* l) {
  __builtin_amdgcn_global_load_lds(
      (const __attribute__((address_space(1))) void*)g,
      (__attribute__((address_space(3))) void*)l, 16, 0, 0);
}

// ---------------- fused fp32 -> bf16 weight convert (7 tensors, contiguous dst) ----------------
__global__ __launch_bounds__(256) void cvt_all_kernel(
    const float* __restrict__ s0, const float* __restrict__ s1, const float* __restrict__ s2,
    const float* __restrict__ s3, const float* __restrict__ s4, const float* __restrict__ s5,
    const float* __restrict__ s6, bf16* __restrict__ dbase) {
  size_t c = (size_t)blockIdx.x * 256 + threadIdx.x;   // chunk of 8 elements
  const float* src; size_t base;
  if (c < 524288) {
    int seg = (int)(c >> 17);
    src = (seg == 0) ? s0 : (seg == 1) ? s1 : (seg == 2) ? s2 : s3;
    base = (size_t)seg << 17;
  } else if (c < 1048576) { src = s4; base = 524288; }
  else if (c < 1572864)   { src = s5; base = 1048576; }
  else                    { src = s6; base = 1572864; }
  size_t lo = (c - base) * 8;
  float4 v0 = *(const float4*)(src + lo);
  float4 v1 = *(const float4*)(src + lo + 4);
  short8 o;
  o[0] = bfb(v0.x); o[1] = bfb(v0.y); o[2] = bfb(v0.z); o[3] = bfb(v0.w);
  o[4] = bfb(v1.x); o[5] = bfb(v1.y); o[6] = bfb(v1.z); o[7] = bfb(v1.w);
  *(short8*)(dbase + c * 8) = o;
}

// ---------------- t projections: out[s][b][n] = t[b] . W_s[n] ----------------
__global__ __launch_bounds__(256) void tproj_kernel(const float* __restrict__ t,
    const float* __restrict__ w0, const float* __restrict__ w1, const float* __restrict__ w2,
    const float* __restrict__ w3, const float* __restrict__ w4, const float* __restrict__ w5,
    float* __restrict__ out) {
  int gid = blockIdx.x * 256 + threadIdx.x;       // 6*4*1024 = 24576
  int s = gid >> 12, rem = gid & 4095;
  int b = rem >> 10, n = rem & 1023;
  const float* w = (s == 0) ? w0 : (s == 1) ? w1 : (s == 2) ? w2 : (s == 3) ? w3 : (s == 4) ? w4 : w5;
  const float4* tv = (const float4*)(t + b * 256);
  const float4* wv = (const float4*)(w + n * 256);
  float acc = 0.f;
  #pragma unroll 8
  for (int j = 0; j < 64; ++j) {
    float4 a = tv[j], c = wv[j];
    acc += a.x * c.x + a.y * c.y + a.z * c.z + a.w * c.w;
  }
  out[gid] = acc;
}

// ---------------- AdaRMSNorm ----------------
__global__ __launch_bounds__(256) void ada_rms_kernel(const float* __restrict__ x,
    const float* __restrict__ gamma, const float* __restrict__ beta, bf16* __restrict__ out) {
  int row = blockIdx.x;            // 8192 rows
  int b = row >> 11;
  int tid = threadIdx.x;
  const float* xr = x + (size_t)row * 1024;
  float4 v = *(const float4*)(xr + tid * 4);
  float ss = v.x * v.x + v.y * v.y + v.z * v.z + v.w * v.w;
  #pragma unroll
  for (int m = 1; m < 64; m <<= 1) ss += __shfl_xor(ss, m);
  __shared__ float red[4];
  if ((tid & 63) == 0) red[tid >> 6] = ss;
  __syncthreads();
  float tot = red[0] + red[1] + red[2] + red[3];
  float rinv = rsqrtf(tot * (1.0f / 1024.0f) + 1e-6f);
  const float* g  = gamma + b * 1024 + tid * 4;
  const float* be = beta  + b * 1024 + tid * 4;
  short4v o;
  o[0] = bfb(g[0] * v.x * rinv + be[0]);
  o[1] = bfb(g[1] * v.y * rinv + be[1]);
  o[2] = bfb(g[2] * v.z * rinv + be[2]);
  o[3] = bfb(g[3] * v.w * rinv + be[3]);
  *(short4v*)(out + (size_t)row * 1024 + tid * 4) = o;
}

// ---------------- bf16 MFMA GEMM (m97 structure): C[M,N] = A[M,K] . B[N,K]^T ----------------
enum { EPI_HEADS = 0, EPI_VTRANS = 1, EPI_RESID = 2, EPI_FINAL = 3 };

template<int EPI>
__global__ __launch_bounds__(256) void gemm_bt_kernel(
    const bf16* __restrict__ A, const bf16* __restrict__ B,
    int N, int K,
    float* __restrict__ outF, bf16* __restrict__ outB,
    const float* __restrict__ aux1, const float* __restrict__ aux2,
    const float* __restrict__ bias)
{
  __shared__ __align__(16) bf16 As[128][32];   // linear: required by global_load_lds
  __shared__ __align__(16) bf16 Bs[128][32];
  const int tid = threadIdx.x;
  const int lane = tid & 63, wid = tid >> 6;
  const int wr = wid >> 1, wc = wid & 1;              // 2x2 wave grid, 64x64 per wave
  const int ntn = N >> 7;
  const int trow = (int)(blockIdx.x / ntn) << 7;
  const int tcol = (int)(blockIdx.x % ntn) << 7;
  const int fr = lane & 15, fc = (lane >> 4) << 3;
  const int rbase = (lane >> 4) << 2;
  // staging: wave wid covers rows [wid*32, wid*32+32) in two 1KB issues
  const bf16* gA0 = A + (size_t)(trow + wid * 32 + (lane >> 2)) * K + ((lane & 3) << 3);
  const bf16* gA1 = gA0 + (size_t)16 * K;
  const bf16* gB0 = B + (size_t)(tcol + wid * 32 + (lane >> 2)) * K + ((lane & 3) << 3);
  const bf16* gB1 = gB0 + (size_t)16 * K;
  bf16* lA0 = &As[wid * 32][0];
  bf16* lA1 = &As[wid * 32 + 16][0];
  bf16* lB0 = &Bs[wid * 32][0];
  bf16* lB1 = &Bs[wid * 32 + 16][0];
  f32x4 acc[4][4] = {};
  for (int k0 = 0; k0 < K; k0 += 32) {
    __syncthreads();                 // prior frag reads done
    gld_lds16(gA0 + k0, lA0);
    gld_lds16(gA1 + k0, lA1);
    gld_lds16(gB0 + k0, lB0);
    gld_lds16(gB1 + k0, lB1);
    __syncthreads();                 // vmcnt(0) drained here by compiler
    short8 af[4], bfr[4];
    #pragma unroll
    for (int m = 0; m < 4; ++m) af[m] = *(const short8*)&As[wr * 64 + m * 16 + fr][fc];
    #pragma unroll
    for (int n = 0; n < 4; ++n) bfr[n] = *(const short8*)&Bs[wc * 64 + n * 16 + fr][fc];
    #pragma unroll
    for (int m = 0; m < 4; ++m)
      #pragma unroll
      for (int n = 0; n < 4; ++n)
        acc[m][n] = __builtin_amdgcn_mfma_f32_16x16x32_bf16(af[m], bfr[n], acc[m][n], 0, 0, 0);
  }
  #pragma unroll
  for (int m = 0; m < 4; ++m)
  #pragma unroll
  for (int n = 0; n < 4; ++n)
  #pragma unroll
  for (int r = 0; r < 4; ++r) {
    int row = trow + wr * 64 + m * 16 + rbase + r;
    int col = tcol + wc * 64 + n * 16 + fr;
    float c = acc[m][n][r];
    if constexpr (EPI == EPI_HEADS) {            // [b,h,l,d] bf16
      int b = row >> 11, l = row & 2047, h = col >> 6, dd = col & 63;
      outB[(((size_t)(b * 16 + h) * 2048 + l) << 6) + dd] = __float2bfloat16(c);
    } else if constexpr (EPI == EPI_VTRANS) {    // [b,h,d,l] bf16
      int b = row >> 11, l = row & 2047, h = col >> 6, dd = col & 63;
      outB[(((size_t)(b * 16 + h) * 64 + dd) << 11) + l] = __float2bfloat16(c);
    } else if constexpr (EPI == EPI_RESID) {     // xmid = x + alpha * c  (fp32)
      int b = row >> 11;
      size_t idx = (size_t)row * 1024 + col;
      outF[idx] = aux1[idx] + aux2[b * 1024 + col] * c;
    } else {                                     // EPI_FINAL: out = xmid + alpha*(c + bias)
      int b = row >> 11;
      size_t idx = (size_t)row * 1024 + col;
      outF[idx] = aux1[idx] + aux2[b * 1024 + col] * (c + bias[col]);
    }
  }
}

// ---------------- fused SwiGLU: gh = silu(x@gw^T) * (x@hw^T), 128x64 tiles ----------------
__global__ __launch_bounds__(256) void swiglu_kernel(
    const bf16* __restrict__ A, const bf16* __restrict__ Bg, const bf16* __restrict__ Bh,
    bf16* __restrict__ outB)
{
  __shared__ __align__(16) bf16 As[128][32];
  __shared__ __align__(16) bf16 Gs[64][32];
  __shared__ __align__(16) bf16 Hs[64][32];
  const int tid = threadIdx.x, lane = tid & 63, wid = tid >> 6;
  const int wr = wid >> 1, wc = wid & 1;              // per wave 64x32 output
  const int trow = (int)(blockIdx.x >> 6) << 7;       // 64 row tiles
  const int tcol = (int)(blockIdx.x & 63) << 6;       // 64 col tiles (4096/64)
  const int fr = lane & 15, fc = (lane >> 4) << 3, rbase = (lane >> 4) << 2;
  const bf16* gA0 = A  + (size_t)(trow + wid * 32 + (lane >> 2)) * 1024 + ((lane & 3) << 3);
  const bf16* gA1 = gA0 + (size_t)16 * 1024;
  const bf16* gG  = Bg + (size_t)(tcol + wid * 16 + (lane >> 2)) * 1024 + ((lane & 3) << 3);
  const bf16* gH  = Bh + (size_t)(tcol + wid * 16 + (lane >> 2)) * 1024 + ((lane & 3) << 3);
  bf16* lA0 = &As[wid * 32][0];
  bf16* lA1 = &As[wid * 32 + 16][0];
  bf16* lG  = &Gs[wid * 16][0];
  bf16* lH  = &Hs[wid * 16][0];
  f32x4 accg[4][2] = {}, acch[4][2] = {};
  for (int k0 = 0; k0 < 1024; k0 += 32) {
    __syncthreads();
    gld_lds16(gA0 + k0, lA0);
    gld_lds16(gA1 + k0, lA1);
    gld_lds16(gG + k0, lG);
    gld_lds16(gH + k0, lH);
    __syncthreads();
    short8 af[4], gf[2], hf[2];
    #pragma unroll
    for (int m = 0; m < 4; ++m) af[m] = *(const short8*)&As[wr * 64 + m * 16 + fr][fc];
    #pragma unroll
    for (int n = 0; n < 2; ++n) {
      gf[n] = *(const short8*)&Gs[wc * 32 + n * 16 + fr][fc];
      hf[n] = *(const short8*)&Hs[wc * 32 + n * 16 + fr][fc];
    }
    #pragma unroll
    for (int m = 0; m < 4; ++m)
      #pragma unroll
      for (int n = 0; n < 2; ++n) {
        accg[m][n] = __builtin_amdgcn_mfma_f32_16x16x32_bf16(af[m], gf[n], accg[m][n], 0, 0, 0);
        acch[m][n] = __builtin_amdgcn_mfma_f32_16x16x32_bf16(af[m], hf[n], acch[m][n], 0, 0, 0);
      }
  }
  #pragma unroll
  for (int m = 0; m < 4; ++m)
  #pragma unroll
  for (int n = 0; n < 2; ++n)
  #pragma unroll
  for (int r = 0; r < 4; ++r) {
    int row = trow + wr * 64 + m * 16 + rbase + r;
    int col = tcol + wc * 32 + n * 16 + fr;
    float g = accg[m][n][r];
    float sg = g / (1.f + __expf(-g));
    outB[(size_t)row * 4096 + col] = __float2bfloat16(sg * acch[m][n][r]);
  }
}

// ---------------- flash attention: swapped QK^T, in-lane softmax denom, packed P ----------------
__global__ __launch_bounds__(256) void attn_kernel(const bf16* __restrict__ q,
    const bf16* __restrict__ k, const bf16* __restrict__ vt, bf16* __restrict__ o) {
  // XCD-aware swizzle: 16 q-tiles of one (b,h) stay on one XCD (share K/V in L2)
  const int id = blockIdx.x;
  const int bh = (id & 7) * 8 + ((id >> 3) >> 4);
  const int qt = (id >> 3) & 15;
  const int b = bh >> 4, h = bh & 15;
  __shared__ __align__(16) bf16 Ks[64][72];   // [kk][d]
  __shared__ __align__(16) bf16 Vs[64][72];   // [d][kk]
  __shared__ __align__(16) bf16 Ps[128][72];  // [q_local][kk]
  const int tid = threadIdx.x, lane = tid & 63, w = tid >> 6;
  const int fr = lane & 15, hi = lane >> 4;
  const int fc = hi << 3, rbase = hi << 2;
  const bf16* qbase = q + ((size_t)bh * 2048 + qt * 128) * 64;
  const bf16* kbase = k + (size_t)bh * 2048 * 64;
  const bf16* vbase = vt + (size_t)bh * 64 * 2048;
  short8 qf[2][2];
  #pragma unroll
  for (int nq = 0; nq < 2; ++nq)
    #pragma unroll
    for (int ks = 0; ks < 2; ++ks)
      qf[nq][ks] = *(const short8*)(qbase + (size_t)(w * 32 + nq * 16 + fr) * 64 + ks * 32 + fc);
  f32x4 accO[4][2] = {};   // [nd][nq]  O^T: d rows, q cols
  float den[2] = {};
  const float cf = 0.125f * 1.44269504089f;
  const int sr = tid >> 3, sc = (tid & 7) << 3;
  // prefetch first tile into regs
  short8 rk0 = *(const short8*)(kbase + (size_t)sr * 64 + sc);
  short8 rk1 = *(const short8*)(kbase + (size_t)(sr + 32) * 64 + sc);
  short8 rv0 = *(const short8*)(vbase + (size_t)sr * 2048 + sc);
  short8 rv1 = *(const short8*)(vbase + (size_t)(sr + 32) * 2048 + sc);
  for (int kt = 0; kt < 2048; kt += 64) {
    __syncthreads();                 // prior tile's LDS reads done
    *(short8*)&Ks[sr][sc]      = rk0;
    *(short8*)&Ks[sr + 32][sc] = rk1;
    *(short8*)&Vs[sr][sc]      = rv0;
    *(short8*)&Vs[sr + 32][sc] = rv1;
    __syncthreads();
    if (kt + 64 < 2048) {            // T14: issue next-tile loads, consume next iter
      rk0 = *(const short8*)(kbase + (size_t)(kt + 64 + sr) * 64 + sc);
      rk1 = *(const short8*)(kbase + (size_t)(kt + 96 + sr) * 64 + sc);
      rv0 = *(const short8*)(vbase + (size_t)sr * 2048 + kt + 64 + sc);
      rv1 = *(const short8*)(vbase + (size_t)(sr + 32) * 2048 + kt + 64 + sc);
    }
    // S^T[kk][q] = mfma(K-frag, Q-frag)
    f32x4 s[4][2] = {};
    #pragma unroll
    for (int ks = 0; ks < 2; ++ks) {
      short8 kf[4];
      #pragma unroll
      for (int mk = 0; mk < 4; ++mk) kf[mk] = *(const short8*)&Ks[mk * 16 + fr][ks * 32 + fc];
      #pragma unroll
      for (int mk = 0; mk < 4; ++mk)
        #pragma unroll
        for (int nq = 0; nq < 2; ++nq)
          s[mk][nq] = __builtin_amdgcn_mfma_f32_16x16x32_bf16(kf[mk], qf[nq][ks], s[mk][nq], 0, 0, 0);
    }
    // exp2 + in-lane denom + packed b64 P write (P^T lane layout -> P[q][kk] rows)
    #pragma unroll
    for (int mk = 0; mk < 4; ++mk)
      #pragma unroll
      for (int nq = 0; nq < 2; ++nq) {
        short4v pk;
        float d0 = exp2f(cf * s[mk][nq][0]);
        float d1 = exp2f(cf * s[mk][nq][1]);
        float d2 = exp2f(cf * s[mk][nq][2]);
        float d3 = exp2f(cf * s[mk][nq][3]);
        pk[0] = bfb(d0); pk[1] = bfb(d1); pk[2] = bfb(d2); pk[3] = bfb(d3);
        den[nq] += (d0 + d1) + (d2 + d3);
        *(short4v*)&Ps[w * 32 + nq * 16 + fr][mk * 16 + rbase] = pk;
      }
    __syncthreads();   // Ps visible (same-wave rows, but keep ordering robust)
    // O^T += mfma(V^T-frag, P-frag)
    #pragma unroll
    for (int ks2 = 0; ks2 < 2; ++ks2) {
      short8 av[4], bp[2];
      #pragma unroll
      for (int nd = 0; nd < 4; ++nd) av[nd] = *(const short8*)&Vs[nd * 16 + fr][ks2 * 32 + fc];
      #pragma unroll
      for (int nq = 0; nq < 2; ++nq) bp[nq] = *(const short8*)&Ps[w * 32 + nq * 16 + fr][ks2 * 32 + fc];
      #pragma unroll
      for (int nd = 0; nd < 4; ++nd)
        #pragma unroll
        for (int nq = 0; nq < 2; ++nq)
          accO[nd][nq] = __builtin_amdgcn_mfma_f32_16x16x32_bf16(av[nd], bp[nq], accO[nd][nq], 0, 0, 0);
    }
  }
  // final denom reduce across hi groups (lanes fr, fr+16, fr+32, fr+48)
  float rd[2];
  #pragma unroll
  for (int nq = 0; nq < 2; ++nq) {
    float d = den[nq];
    d += __shfl_xor(d, 16);
    d += __shfl_xor(d, 32);
    rd[nq] = 1.0f / d;
  }
  #pragma unroll
  for (int nd = 0; nd < 4; ++nd)
    #pragma unroll
    for (int nq = 0; nq < 2; ++nq) {
      short4v ov;
      #pragma unroll
      for (int r = 0; r < 4; ++r) ov[r] = bfb(accO[nd][nq][r] * rd[nq]);
      int qrow = qt * 128 + w * 32 + nq * 16 + fr;
      int col = h * 64 + nd * 16 + rbase;
      *(short4v*)&o[((size_t)b * 2048 + qrow) * 1024 + col] = ov;
    }
}

extern "C" void kernel_launch(void* const* d_in, const int* in_sizes, int n_in,
                              void* d_out, int out_size, void* d_ws, size_t ws_size,
                              hipStream_t stream) {
  (void)in_sizes; (void)n_in; (void)out_size; (void)ws_size;
  const float* x   = (const float*)d_in[0];
  const float* t   = (const float*)d_in[1];
  const float* agw = (const float*)d_in[2];
  const float* abw = (const float*)d_in[3];
  const float* wq  = (const float*)d_in[4];
  const float* wk  = (const float*)d_in[5];
  const float* wv  = (const float*)d_in[6];
  const float* wo  = (const float*)d_in[7];
  const float* aaw = (const float*)d_in[8];
  const float* fgw = (const float*)d_in[9];
  const float* fbw = (const float*)d_in[10];
  const float* gw  = (const float*)d_in[11];
  const float* hw  = (const float*)d_in[12];
  const float* ow  = (const float*)d_in[13];
  const float* ob  = (const float*)d_in[14];
  const float* faw = (const float*)d_in[15];
  float* out = (float*)d_out;

  char* p = (char*)d_ws;
  auto alloc = [&](size_t bytes) -> char* {
    char* r = p; p += (bytes + 255) & ~(size_t)255; return r;
  };
  float* tp    = (float*)alloc((size_t)6 * 4096 * 4);
  bf16* wq_b   = (bf16*)alloc((size_t)1024 * 1024 * 2);   // contiguous block for cvt_all:
  bf16* wk_b   = (bf16*)alloc((size_t)1024 * 1024 * 2);
  bf16* wv_b   = (bf16*)alloc((size_t)1024 * 1024 * 2);
  bf16* wo_b   = (bf16*)alloc((size_t)1024 * 1024 * 2);
  bf16* wg_b   = (bf16*)alloc((size_t)4096 * 1024 * 2);
  bf16* wh_b   = (bf16*)alloc((size_t)4096 * 1024 * 2);
  bf16* wout_b = (bf16*)alloc((size_t)1024 * 4096 * 2);
  bf16* xn_b   = (bf16*)alloc((size_t)8192 * 1024 * 2);
  bf16* q_b    = (bf16*)alloc((size_t)8192 * 1024 * 2);
  bf16* k_b    = (bf16*)alloc((size_t)8192 * 1024 * 2);
  bf16* vt_b   = (bf16*)alloc((size_t)8192 * 1024 * 2);
  bf16* ao_b   = (bf16*)alloc((size_t)8192 * 1024 * 2);
  float* xmid  = (float*)alloc((size_t)8192 * 1024 * 4);
  bf16* gh_b   = (bf16*)alloc((size_t)8192 * 4096 * 2);

  // fused weight converts (wq_b..wout_b are contiguous in ws)
  cvt_all_kernel<<<8192, 256, 0, stream>>>(wq, wk, wv, wo, gw, hw, ow, wq_b);
  // t projections: [0]=a_gamma [1]=a_beta [2]=a_alpha [3]=f_gamma [4]=f_beta [5]=f_alpha
  tproj_kernel<<<96, 256, 0, stream>>>(t, agw, abw, aaw, fgw, fbw, faw, tp);
  // attn AdaRMSNorm
  ada_rms_kernel<<<8192, 256, 0, stream>>>(x, tp + 0 * 4096, tp + 1 * 4096, xn_b);
  // QKV
  gemm_bt_kernel<EPI_HEADS> <<<512, 256, 0, stream>>>(xn_b, wq_b, 1024, 1024, nullptr, q_b,  nullptr, nullptr, nullptr);
  gemm_bt_kernel<EPI_HEADS> <<<512, 256, 0, stream>>>(xn_b, wk_b, 1024, 1024, nullptr, k_b,  nullptr, nullptr, nullptr);
  gemm_bt_kernel<EPI_VTRANS><<<512, 256, 0, stream>>>(xn_b, wv_b, 1024, 1024, nullptr, vt_b, nullptr, nullptr, nullptr);
  // attention
  attn_kernel<<<1024, 256, 0, stream>>>(q_b, k_b, vt_b, ao_b);
  // O projection + residual
  gemm_bt_kernel<EPI_RESID><<<512, 256, 0, stream>>>(ao_b, wo_b, 1024, 1024, xmid, nullptr, x, tp + 2 * 4096, nullptr);
  // ffn AdaRMSNorm
  ada_rms_kernel<<<8192, 256, 0, stream>>>(xmid, tp + 3 * 4096, tp + 4 * 4096, xn_b);
  // fused SwiGLU (gate + hidden + silu*mul)
  swiglu_kernel<<<4096, 256, 0, stream>>>(xn_b, wg_b, wh_b, gh_b);
  // out projection + bias + residual
  gemm_bt_kernel<EPI_FINAL> <<<512, 256, 0, stream>>>(gh_b, wout_b, 1024, 4096, out, nullptr, xmid, tp + 5 * 4096, ob);
}